// Round 6
// baseline (98.333 us; speedup 1.0000x reference)
//
#include <hip/hip_runtime.h>
#include <hip/hip_cooperative_groups.h>

namespace cg = cooperative_groups;

// Problem constants
#define HDIM 2048
#define NUM_V 32
#define NUM_K 16
#define DK 128
#define DV 128
#define KEY_DIM 2048          // NUM_K*DK
#define VALUE_DIM 4096        // NUM_V*DV
#define CONV_DIM 8192         // 2*KEY_DIM+VALUE_DIM
#define TOTAL_ROWS 12352      // 8192 + 4096 + 32 + 32

// ws layout (floats):
//  [0,      8192)  conv_out   (q | k | v)
//  [8192,  12288)  z
//  [12288, 12320)  b
//  [12320, 12352)  a
//  [12352, 16448)  out_vec (4096)

// d_out layout (floats): [0,2048) hidden_out | [2048,34816) new_conv_state (8192x4)
//                        | [34816, 559104) rec (32x128x128)

typedef __attribute__((ext_vector_type(4))) float f32x4;

// Single fused cooperative kernel: phase1 GEMV -> sync -> phase2 rec -> sync -> phase3 GEMV.
// 512 threads/block (8 waves); __launch_bounds__(512,4) caps VGPR<=128 -> >=2 blocks/CU
// co-resident -> grid of 512 blocks is always a valid cooperative launch.
__global__ __launch_bounds__(512, 4) void fused(
    const float* __restrict__ h,          // 2048
    const float* __restrict__ Wqkv,       // 8192 x 2048
    const float* __restrict__ Wz,         // 4096 x 2048
    const float* __restrict__ Wb,         // 32 x 2048
    const float* __restrict__ Wa,         // 32 x 2048
    const float* __restrict__ Wout,       // 2048 x 4096
    const float* __restrict__ conv_state, // 8192 x 4
    const float* __restrict__ conv_w,     // 8192 x 4
    const float* __restrict__ rec_in,     // 32 x 128 x 128
    const float* __restrict__ dt_bias,    // 32
    const float* __restrict__ A_log,      // 32
    const float* __restrict__ norm_w,     // 128
    float* __restrict__ ws,
    float* __restrict__ out)              // d_out
{
    cg::grid_group grid = cg::this_grid();

    const int t      = threadIdx.x;
    const int lane   = t & 63;
    const int wid    = t >> 6;                       // 0..7
    const int gwave  = blockIdx.x * 8 + wid;
    const int nwaves = gridDim.x * 8;

    float* out_vec    = ws + 12352;
    float* hidden_out = out;
    float* new_conv   = out + 2048;
    float* rec_out    = out + 2048 + CONV_DIM * 4;   // out + 34816

    // ---------------- phase 1: fused GEMV (Wqkv | Wz | Wb | Wa) @ h ----------
    for (int row = gwave; row < TOTAL_ROWS; row += nwaves) {
        const float* wrow;
        if (row < 8192)       wrow = Wqkv + (size_t)row * HDIM;
        else if (row < 12288) wrow = Wz   + (size_t)(row - 8192) * HDIM;
        else if (row < 12320) wrow = Wb   + (size_t)(row - 12288) * HDIM;
        else                  wrow = Wa   + (size_t)(row - 12320) * HDIM;

        float acc = 0.f;
#pragma unroll
        for (int i = 0; i < 8; ++i) {
            const int idx = (i * 64 + lane) * 4;
            f32x4 w4 = *reinterpret_cast<const f32x4*>(wrow + idx);
            f32x4 h4 = *reinterpret_cast<const f32x4*>(h + idx);
            acc += w4.x * h4.x + w4.y * h4.y + w4.z * h4.z + w4.w * h4.w;
        }
#pragma unroll
        for (int off = 32; off > 0; off >>= 1)
            acc += __shfl_down(acc, off, 64);

        if (lane == 0) {
            if (row < 8192) {
                f32x4 cs = *reinterpret_cast<const f32x4*>(conv_state + row * 4);
                f32x4 cw = *reinterpret_cast<const f32x4*>(conv_w + row * 4);
                float pre = cs.y * cw.x + cs.z * cw.y + cs.w * cw.z + acc * cw.w;
                ws[row] = pre / (1.f + expf(-pre));          // silu -> conv_out
                f32x4 n; n.x = cs.y; n.y = cs.z; n.z = cs.w; n.w = acc;
                *reinterpret_cast<f32x4*>(new_conv + row * 4) = n;
            } else {
                ws[row] = acc;                               // z | b | a
            }
        }
    }

    grid.sync();

    // ---------------- phase 2: per-head recurrent state update ---------------
    __shared__ float s_k[128];
    __shared__ float s_q[128];
    __shared__ float s_delta[128];
    __shared__ float s_part[4][128];
    __shared__ float s_red[4];

    for (int hh = blockIdx.x; hh < NUM_V; hh += gridDim.x) {
        const int d   = t & 127;
        const int kkb = t >> 7;          // 0..3, owns kk in [kkb*32, kkb*32+32)
        const int kh  = hh >> 1;         // key head (VPK = 2)

        const float bv    = ws[12288 + hh];
        const float av    = ws[12320 + hh];
        const float beta  = 1.f / (1.f + expf(-bv));
        const float x     = av + dt_bias[hh];
        const float sp    = fmaxf(x, 0.f) + log1pf(expf(-fabsf(x)));   // softplus
        const float decay = expf(-expf(A_log[hh]) * sp);

        float qr = 0.f, kr = 0.f;
        if (t < 128) {
            qr = ws[kh * 128 + d];
            kr = ws[KEY_DIM + kh * 128 + d];
            float sq = qr * qr, sk = kr * kr;
#pragma unroll
            for (int off = 32; off > 0; off >>= 1) {
                sq += __shfl_down(sq, off, 64);
                sk += __shfl_down(sk, off, 64);
            }
            if ((t & 63) == 0) { s_red[t >> 6] = sq; s_red[2 + (t >> 6)] = sk; }
        }
        __syncthreads();
        if (t < 128) {
            const float ssq = s_red[0] + s_red[1];
            const float ssk = s_red[2] + s_red[3];
            s_q[d] = qr * rsqrtf(ssq + 1e-6f) * 0.08838834764831845f;  // l2n * 1/sqrt(DK)
            s_k[d] = kr * rsqrtf(ssk + 1e-6f);
        }
        __syncthreads();

        const float* rrow = rec_in  + (size_t)hh * (DK * DV) + kkb * 32 * DV;
        float*       wrow = rec_out + (size_t)hh * (DK * DV) + kkb * 32 * DV;

        float kvp = 0.f;
#pragma unroll 8
        for (int i = 0; i < 32; ++i)
            kvp += rrow[i * DV + d] * s_k[kkb * 32 + i];
        s_part[kkb][d] = kvp;
        __syncthreads();

        if (t < 128) {
            float kv = (s_part[0][d] + s_part[1][d]) + (s_part[2][d] + s_part[3][d]);
            kv *= decay;
            const float vv = ws[2 * KEY_DIM + hh * 128 + d];
            s_delta[d] = (vv - kv) * beta;
        }
        __syncthreads();

        const float dlt = s_delta[d];
        float corep = 0.f;
#pragma unroll 8
        for (int i = 0; i < 32; ++i) {
            const float r = rrow[i * DV + d] * decay + s_k[kkb * 32 + i] * dlt;
            wrow[i * DV + d] = r;
            corep += r * s_q[kkb * 32 + i];
        }
        s_part[kkb][d] = corep;
        __syncthreads();

        if (t < 128) {
            const float core = (s_part[0][d] + s_part[1][d]) + (s_part[2][d] + s_part[3][d]);
            float sc = core * core;
#pragma unroll
            for (int off = 32; off > 0; off >>= 1)
                sc += __shfl_down(sc, off, 64);
            if ((t & 63) == 0) s_red[t >> 6] = sc;
            s_delta[d] = core;            // stash core for after the sync
        }
        __syncthreads();
        if (t < 128) {
            const float core = s_delta[d];
            const float ssc  = s_red[0] + s_red[1];
            const float xn   = core * rsqrtf(ssc * (1.f / 128.f) + 1e-6f) * norm_w[d];
            const float zv   = ws[8192 + hh * 128 + d];
            out_vec[hh * 128 + d] = xn * (zv / (1.f + expf(-zv)));   // xn * silu(z)
        }
        __syncthreads();
    }

    grid.sync();

    // ---------------- phase 3: hidden_out = Wout @ out_vec -------------------
    for (int row = gwave; row < HDIM; row += nwaves) {
        const float* wrow = Wout + (size_t)row * VALUE_DIM;
        float acc = 0.f;
#pragma unroll
        for (int i = 0; i < 16; ++i) {
            const int idx = (i * 64 + lane) * 4;
            f32x4 w4 = *reinterpret_cast<const f32x4*>(wrow + idx);
            f32x4 o4 = *reinterpret_cast<const f32x4*>(out_vec + idx);
            acc += w4.x * o4.x + w4.y * o4.y + w4.z * o4.z + w4.w * o4.w;
        }
#pragma unroll
        for (int off = 32; off > 0; off >>= 1)
            acc += __shfl_down(acc, off, 64);
        if (lane == 0) hidden_out[row] = acc;
    }
}

extern "C" void kernel_launch(void* const* d_in, const int* in_sizes, int n_in,
                              void* d_out, int out_size, void* d_ws, size_t ws_size,
                              hipStream_t stream) {
    const float* hidden_in  = (const float*)d_in[0];
    const float* conv_state = (const float*)d_in[1];
    const float* rec_state  = (const float*)d_in[2];
    const float* W_qkv      = (const float*)d_in[3];
    const float* W_z        = (const float*)d_in[4];
    const float* W_b        = (const float*)d_in[5];
    const float* W_a        = (const float*)d_in[6];
    const float* W_out      = (const float*)d_in[7];
    const float* conv_w     = (const float*)d_in[8];
    const float* dt_bias    = (const float*)d_in[9];
    const float* A_log      = (const float*)d_in[10];
    const float* norm_w     = (const float*)d_in[11];

    float* out = (float*)d_out;
    float* ws  = (float*)d_ws;

    // Deterministic grid sizing: occupancy-clamped, capped at 512 (2 blocks/CU on 256 CUs).
    int maxb = 0;
    if (hipOccupancyMaxActiveBlocksPerMultiprocessor(&maxb, fused, 512, 0) != hipSuccess
        || maxb < 1)
        maxb = 1;
    int grid = maxb * 256;
    if (grid > 512) grid = 512;

    void* args[] = {
        (void*)&hidden_in, (void*)&W_qkv, (void*)&W_z, (void*)&W_b, (void*)&W_a,
        (void*)&W_out, (void*)&conv_state, (void*)&conv_w, (void*)&rec_state,
        (void*)&dt_bias, (void*)&A_log, (void*)&norm_w, (void*)&ws, (void*)&out
    };
    hipLaunchCooperativeKernel((void*)fused, dim3(grid), dim3(512), args, 0, stream);
}